// Round 1
// baseline (522.478 us; speedup 1.0000x reference)
//
#include <hip/hip_runtime.h>
#include <cmath>
#include <complex>

typedef unsigned short u16;
typedef __bf16 bf16x8 __attribute__((ext_vector_type(8)));
typedef float f32x4 __attribute__((ext_vector_type(4)));

#define CD 128
#define TILE_N 8
#define XS 136   // bufX / sTP row stride in elements (272 B, 16B-aligned, +8 pad)
#define LS 128   // sL / sR row stride in elements (b16 access only)

// region0: bufX (64 x XS) aliased with sTP (72 x XS) = 9792 elems
// sL: 64*LS = 8192 ; sR: 8192.  total 26176 u16 = 52352 B  (<64 KB, 3 blocks/CU)
#define SMEM_TOTAL (72 * XS + 64 * LS + 64 * LS)

struct TPW { float w220[25]; float w121[45]; float w112[45]; };

__device__ __forceinline__ u16 f2b(float f) {
  unsigned u = __float_as_uint(f);
  u += 0x7fffu + ((u >> 16) & 1u);
  return (u16)(u >> 16);
}
__device__ __forceinline__ float b2f(u16 h) {
  return __uint_as_float(((unsigned)h) << 16);
}

__global__ void cvt_weights_kernel(const float* __restrict__ Wl,
                                   const float* __restrict__ Wr,
                                   const float* __restrict__ Wf,
                                   u16* __restrict__ ws) {
  int idx = blockIdx.x * 256 + threadIdx.x;   // 0..147455 exactly
  const float* src; int off;
  if (idx < 49152)      { src = Wl; off = idx; }
  else if (idx < 98304) { src = Wr; off = idx - 49152; }
  else                  { src = Wf; off = idx - 98304; }
  ws[idx] = f2b(src[off]);
}

__global__ __launch_bounds__(256, 3)
void fused_kernel(const float* __restrict__ x, const u16* __restrict__ ws,
                  const float* __restrict__ bfin, float* __restrict__ out,
                  int N, TPW tw) {
  __shared__ __align__(16) u16 smem[SMEM_TOTAL];
  u16* bufX = smem;                       // 64 x XS  (rows: (m-1)*8+n, m=1..8)
  u16* sTP  = smem;                       // 72 x XS  (aliases bufX; post-stage-A)
  u16* sL   = smem + 72 * XS;             // 64 x LS  (rows: (m-1)*8+n)
  u16* sR   = smem + 72 * XS + 64 * LS;   // 64 x LS

  const int tid  = threadIdx.x;
  const int n0   = blockIdx.x * TILE_N;
  const int w    = tid >> 6;
  const int lane = tid & 63;
  const int q    = lane >> 4;
  const int lr   = lane & 15;

  // ---------- stage 0: global x (m=1..8) -> bufX (bf16) ----------
#pragma unroll
  for (int it = 0; it < 4; ++it) {
    int e = (it * 256 + tid) * 8;   // element index over [64 rows][128 c]
    int r = e >> 7;                 // 0..63 : m = 1 + r/8, n = r%8
    int c = e & 127;
    int n = n0 + (r & 7);
    if (n >= N) n = N - 1;
    int grow = (n * 9 + 1 + (r >> 3)) * CD + c;
    float4 a = *(const float4*)(x + grow);
    float4 b = *(const float4*)(x + grow + 4);
    uint4 v;
    v.x = (unsigned)f2b(a.x) | ((unsigned)f2b(a.y) << 16);
    v.y = (unsigned)f2b(a.z) | ((unsigned)f2b(a.w) << 16);
    v.z = (unsigned)f2b(b.x) | ((unsigned)f2b(b.y) << 16);
    v.w = (unsigned)f2b(b.z) | ((unsigned)f2b(b.w) << 16);
    *(uint4*)(bufX + r * XS + c) = v;
  }
  __syncthreads();

  // ---------- stage A: xl = A*W_left^T, xr = A*W_right^T (l=1,2 only) ----------
  // col-tiles 0..15 over 256 cols (0..127 -> left/sL, 128..255 -> right/sR)
#pragma unroll
  for (int cti = 0; cti < 4; ++cti) {
    int ct   = w * 4 + cti;             // 0..15
    int mat  = ct >> 3;                 // 0 = left, 1 = right
    int dcol = ((ct & 7) << 4) + lr;    // 0..127
    const u16* w1 = ws + (mat * 3 + 1) * 16384 + dcol * CD;
    const u16* w2 = ws + (mat * 3 + 2) * 16384 + dcol * CD;
    uint4 b1[4], b2[4];
#pragma unroll
    for (int kk = 0; kk < 4; ++kk) {
      b1[kk] = *(const uint4*)(w1 + kk * 32 + q * 8);
      b2[kk] = *(const uint4*)(w2 + kk * 32 + q * 8);
    }
    u16* dst = (ct < 8) ? sL : sR;
    // row-tiles: rt 0,1 -> l=1 (24 rows), rt 2,3,4 -> l=2 (40 rows)
#pragma unroll
    for (int rt = 0; rt < 5; ++rt) {
      const int l2f   = (rt >= 2) ? 1 : 0;
      const int rows  = l2f ? 40 : 24;
      const int gbase = l2f ? (rt - 2) * 16 : rt * 16;
      const int boff  = l2f ? 24 : 0;
      int ga = gbase + lr; if (ga > rows - 1) ga = rows - 1;
      const int arow = boff + ga;
      f32x4 acc = {0.f, 0.f, 0.f, 0.f};
#pragma unroll
      for (int kk = 0; kk < 4; ++kk) {
        uint4 av = *(const uint4*)(bufX + arow * XS + kk * 32 + q * 8);
        acc = __builtin_amdgcn_mfma_f32_16x16x32_bf16(
            __builtin_bit_cast(bf16x8, av),
            __builtin_bit_cast(bf16x8, l2f ? b2[kk] : b1[kk]),
            acc, 0, 0, 0);
      }
#pragma unroll
      for (int reg = 0; reg < 4; ++reg) {
        int gg = gbase + q * 4 + reg;
        if (gg < rows) dst[(boff + gg) * LS + dcol] = f2b(acc[reg]);
      }
    }
  }
  __syncthreads();

  // ---------- stage B: channel-wise CG tensor product (fp32), -> sTP ----------
  {
    int c  = tid & 127;
    int nb = tid >> 7;
#pragma unroll
    for (int p = 0; p < 4; ++p) {
      int n = nb * 4 + p;
      float xl1[3], xr1[3], xl2[5], xr2[5];
#pragma unroll
      for (int i = 0; i < 3; ++i) {
        xl1[i] = b2f(sL[(i * 8 + n) * LS + c]);
        xr1[i] = b2f(sR[(i * 8 + n) * LS + c]);
      }
#pragma unroll
      for (int j = 0; j < 5; ++j) {
        xl2[j] = b2f(sL[(24 + j * 8 + n) * LS + c]);
        xr2[j] = b2f(sR[(24 + j * 8 + n) * LS + c]);
      }
      float o0 = 0.f;
#pragma unroll
      for (int i = 0; i < 5; ++i)
#pragma unroll
        for (int j = 0; j < 5; ++j)
          o0 += tw.w220[i * 5 + j] * xl2[i] * xr2[j];
      float o1[3] = {0.f, 0.f, 0.f};
#pragma unroll
      for (int i = 0; i < 3; ++i)
#pragma unroll
        for (int j = 0; j < 5; ++j) {
          float pr = xl1[i] * xr2[j];
#pragma unroll
          for (int k = 0; k < 3; ++k) o1[k] += tw.w121[(i * 5 + j) * 3 + k] * pr;
        }
      float o2[5] = {0.f, 0.f, 0.f, 0.f, 0.f};
#pragma unroll
      for (int i = 0; i < 3; ++i)
#pragma unroll
        for (int j = 0; j < 3; ++j) {
          float pr = xl1[i] * xr1[j];
#pragma unroll
          for (int k = 0; k < 5; ++k) o2[k] += tw.w112[(i * 3 + j) * 5 + k] * pr;
        }
      sTP[(0 * 8 + n) * XS + c] = f2b(o0);
#pragma unroll
      for (int k = 0; k < 3; ++k) sTP[((1 + k) * 8 + n) * XS + c] = f2b(o1[k]);
#pragma unroll
      for (int k = 0; k < 5; ++k) sTP[((4 + k) * 8 + n) * XS + c] = f2b(o2[k]);
    }
  }
  __syncthreads();

  // ---------- stage C: out = TP * W_final^T (+ b_final on m=0), store fp32 ----------
#pragma unroll
  for (int cti = 0; cti < 2; ++cti) {
    int ct   = w + cti * 4;            // 0..7
    int dcol = (ct << 4) + lr;         // 0..127
    float bias = bfin[dcol];
    const u16* wfb = ws + 6 * 16384 + dcol * CD;
#pragma unroll
    for (int l = 0; l < 3; ++l) {
      const u16* wf = wfb + l * 16384;
      uint4 bfrag[4];
#pragma unroll
      for (int kk = 0; kk < 4; ++kk)
        bfrag[kk] = *(const uint4*)(wf + kk * 32 + q * 8);
      const int rows   = (l == 0) ? 8 : (l == 1 ? 24 : 40);
      const int soff   = (l == 0) ? 0 : (l == 1 ? 8 : 32);
      const int ntiles = (l == 0) ? 1 : (l == 1 ? 2 : 3);
      for (int t = 0; t < ntiles; ++t) {
        int ga = t * 16 + lr; if (ga > rows - 1) ga = rows - 1;
        const int arow = soff + ga;
        f32x4 acc = {0.f, 0.f, 0.f, 0.f};
#pragma unroll
        for (int kk = 0; kk < 4; ++kk) {
          uint4 av = *(const uint4*)(sTP + arow * XS + kk * 32 + q * 8);
          acc = __builtin_amdgcn_mfma_f32_16x16x32_bf16(
              __builtin_bit_cast(bf16x8, av),
              __builtin_bit_cast(bf16x8, bfrag[kk]),
              acc, 0, 0, 0);
        }
#pragma unroll
        for (int reg = 0; reg < 4; ++reg) {
          int gg = t * 16 + q * 4 + reg;
          if (gg < rows) {
            int m = l * l + (gg >> 3);
            int n = n0 + (gg & 7);
            if (n < N) {
              float v = acc[reg];
              if (l == 0) v += bias;
              out[(n * 9 + m) * CD + dcol] = v;
            }
          }
        }
      }
    }
  }
}

// =================== host: Wigner-3j (exact port of reference) ===================
typedef std::complex<double> cd;

static double factd(int n) { double r = 1.0; for (int i = 2; i <= n; ++i) r *= i; return r; }

static double su2_cg(int j1, int m1, int j2, int m2, int j3, int m3) {
  if (m3 != m1 + m2) return 0.0;
  int vmin = -j1 + j2 + m3; if (-j1 + m1 > vmin) vmin = -j1 + m1; if (0 > vmin) vmin = 0;
  int vmax = j2 + j3 + m1; if (j3 - j1 + j2 < vmax) vmax = j3 - j1 + j2; if (j3 + m3 < vmax) vmax = j3 + m3;
  double pref = std::sqrt((2.0 * j3 + 1.0) * factd(j3 + j1 - j2) * factd(j3 - j1 + j2)
                          * factd(j1 + j2 - j3) / factd(j1 + j2 + j3 + 1)
                          * factd(j3 + m3) * factd(j3 - m3)
                          / (factd(j1 - m1) * factd(j1 + m1) * factd(j2 - m2) * factd(j2 + m2)));
  double s = 0.0;
  for (int v = vmin; v <= vmax; ++v) {
    double sgn = ((v + j2 + m2) & 1) ? -1.0 : 1.0;
    s += sgn / factd(v) * factd(j2 + j3 + m1 - v) * factd(j1 - m1 + v)
         / (factd(j3 - j1 + j2 - v) * factd(j3 + m3 - v) * factd(v + j1 - j2 - m3));
  }
  return pref * s;
}

static void qmat(int l, cd q[5][5]) {
  for (int a = 0; a < 5; ++a) for (int b = 0; b < 5; ++b) q[a][b] = 0.0;
  const double is2 = 1.0 / std::sqrt(2.0);
  for (int m = -l; m < 0; ++m) {
    q[l + m][l - m] = is2;            // q[l+m, l+|m|]
    q[l + m][l + m] = cd(0.0, -is2);  // q[l+m, l-|m|]
  }
  q[l][l] = 1.0;
  for (int m = 1; m <= l; ++m) {
    double s = (m & 1) ? -1.0 : 1.0;
    q[l + m][l + m] = s * is2;
    q[l + m][l - m] = cd(0.0, s * is2);
  }
  cd f(1.0, 0.0);
  for (int i = 0; i < l; ++i) f *= cd(0.0, -1.0);  // (-1j)^l
  for (int a = 0; a < 5; ++a) for (int b = 0; b < 5; ++b) q[a][b] *= f;
}

static void wigner3j(int l1, int l2, int l3, double* C) {  // flat [d1][d2][d3]
  int d1 = 2 * l1 + 1, d2 = 2 * l2 + 1, d3 = 2 * l3 + 1;
  cd Q1[5][5], Q2[5][5], Q3[5][5];
  qmat(l1, Q1); qmat(l2, Q2); qmat(l3, Q3);
  cd Csu2[5][5][5];
  for (int i = 0; i < d1; ++i)
    for (int k = 0; k < d2; ++k)
      for (int n = 0; n < d3; ++n)
        Csu2[i][k][n] = su2_cg(l1, i - l1, l2, k - l2, l3, n - l3);
  double norm = 0.0;
  for (int j = 0; j < d1; ++j)
    for (int lx = 0; lx < d2; ++lx)
      for (int m = 0; m < d3; ++m) {
        cd acc(0.0, 0.0);
        for (int i = 0; i < d1; ++i)
          for (int k = 0; k < d2; ++k)
            for (int n = 0; n < d3; ++n)
              acc += Q1[i][j] * Q2[k][lx] * std::conj(Q3[n][m]) * Csu2[i][k][n];
        C[(j * d2 + lx) * d3 + m] = acc.real();
        norm += acc.real() * acc.real();
      }
  norm = std::sqrt(norm);
  for (int t = 0; t < d1 * d2 * d3; ++t) C[t] /= norm;
}

extern "C" void kernel_launch(void* const* d_in, const int* in_sizes, int n_in,
                              void* d_out, int out_size, void* d_ws, size_t ws_size,
                              hipStream_t stream) {
  const float* x    = (const float*)d_in[0];
  const float* Wl   = (const float*)d_in[1];
  const float* Wr   = (const float*)d_in[3];
  const float* Wf   = (const float*)d_in[5];
  const float* bfin = (const float*)d_in[6];
  float* out = (float*)d_out;
  const int N = in_sizes[0] / (9 * CD);

  TPW tw;
  double c220[25], c121[45], c112[45];
  wigner3j(2, 2, 0, c220);
  wigner3j(1, 2, 1, c121);
  wigner3j(1, 1, 2, c112);
  const double a1 = std::sqrt(3.0), a2 = std::sqrt(5.0);
  for (int i = 0; i < 25; ++i) tw.w220[i] = (float)c220[i];          // alpha = 1
  for (int i = 0; i < 45; ++i) tw.w121[i] = (float)(a1 * c121[i]);
  for (int i = 0; i < 45; ++i) tw.w112[i] = (float)(a2 * c112[i]);

  u16* ws = (u16*)d_ws;  // 147456 bf16 = 294912 B
  cvt_weights_kernel<<<576, 256, 0, stream>>>(Wl, Wr, Wf, ws);
  int grid = (N + TILE_N - 1) / TILE_N;
  fused_kernel<<<grid, 256, 0, stream>>>(x, ws, bfin, out, N, tw);
}

// Round 2
// 503.450 us; speedup vs baseline: 1.0378x; 1.0378x over previous
//
#include <hip/hip_runtime.h>
#include <cmath>
#include <complex>

typedef unsigned short u16;
typedef unsigned int u32;
typedef __bf16 bf16x8 __attribute__((ext_vector_type(8)));
typedef float f32x4 __attribute__((ext_vector_type(4)));

#define CD 128
#define TILE_N 8
#define XS 136   // bufX / sTP row stride (272 B, 16B-aligned)
#define LS 132   // sL / sR row stride (264 B -> 8-bank rotation per 4 rows: conflict-free)

// region0: bufX (64 x XS) aliased with sTP (72 x XS) = 9792 elems
// sL: 64*LS = 8448 ; sR: 8448.  total 26688 u16 = 53376 B  (3 blocks/CU)
#define SMEM_TOTAL (72 * XS + 64 * LS + 64 * LS)

struct TPW { float w220[25]; float w121[45]; float w112[45]; };

__device__ __forceinline__ u16 f2b(float f) {
  unsigned u = __float_as_uint(f);
  u += 0x7fffu + ((u >> 16) & 1u);
  return (u16)(u >> 16);
}
__device__ __forceinline__ float b2f(u16 h) {
  return __uint_as_float(((unsigned)h) << 16);
}
__device__ __forceinline__ u32 pack2(float a, float b) {
  return (u32)f2b(a) | ((u32)f2b(b) << 16);
}

__global__ void cvt_weights_kernel(const float* __restrict__ Wl,
                                   const float* __restrict__ Wr,
                                   const float* __restrict__ Wf,
                                   u16* __restrict__ ws) {
  int idx = (blockIdx.x * 256 + threadIdx.x) * 8;   // 72 blocks -> 0..147448
  const float* src; int off;
  if (idx < 49152)      { src = Wl; off = idx; }
  else if (idx < 98304) { src = Wr; off = idx - 49152; }
  else                  { src = Wf; off = idx - 98304; }
  float4 a = *(const float4*)(src + off);
  float4 b = *(const float4*)(src + off + 4);
  uint4 v;
  v.x = pack2(a.x, a.y);
  v.y = pack2(a.z, a.w);
  v.z = pack2(b.x, b.y);
  v.w = pack2(b.z, b.w);
  *(uint4*)(ws + idx) = v;
}

__global__ __launch_bounds__(256, 3)
void fused_kernel(const float* __restrict__ x, const u16* __restrict__ ws,
                  const float* __restrict__ bfin, float* __restrict__ out,
                  int N, TPW tw) {
  __shared__ __align__(16) u16 smem[SMEM_TOTAL];
  u16* bufX = smem;                       // 64 x XS  (rows: (m-1)*8+n, m=1..8)
  u16* sTP  = smem;                       // 72 x XS  (aliases bufX; post-stage-A)
  u16* sL   = smem + 72 * XS;             // 64 x LS
  u16* sR   = smem + 72 * XS + 64 * LS;   // 64 x LS

  const int tid  = threadIdx.x;
  const int n0   = blockIdx.x * TILE_N;
  const int w    = tid >> 6;
  const int lane = tid & 63;
  const int q    = lane >> 4;
  const int lr   = lane & 15;

  // ---------- hoisted global loads: stage-A pair-0 B-frags + biases ----------
  const int mat = w >> 1;                 // 0 = left, 1 = right
  const int wl  = w & 1;
  u16* dstA = mat ? sR : sL;
  const u16* wsA = ws + mat * 3 * 16384;

  uint4 bfa[2][2][4];                     // [ci][l-1][kk]
#pragma unroll
  for (int ci = 0; ci < 2; ++ci) {
    int dcol = (wl * 4 + ci) * 16 + lr;
#pragma unroll
    for (int kk = 0; kk < 4; ++kk) {
      bfa[ci][0][kk] = *(const uint4*)(wsA + 16384     + dcol * CD + kk * 32 + q * 8);
      bfa[ci][1][kk] = *(const uint4*)(wsA + 2 * 16384 + dcol * CD + kk * 32 + q * 8);
    }
  }
  const int dc0 = w * 16 + lr;            // stage-C cti0 col
  const int dc1 = dc0 + 64;               // stage-C cti1 col
  float bias0 = bfin[dc0];
  float bias1 = bfin[dc1];

  // ---------- stage 0: global x (m=1..8) -> bufX (bf16) ----------
#pragma unroll
  for (int it = 0; it < 4; ++it) {
    int e = (it * 256 + tid) * 8;   // element index over [64 rows][128 c]
    int r = e >> 7;                 // 0..63 : m = 1 + r/8, n = r%8
    int c = e & 127;
    int n = n0 + (r & 7);
    if (n >= N) n = N - 1;
    int grow = (n * 9 + 1 + (r >> 3)) * CD + c;
    float4 a = *(const float4*)(x + grow);
    float4 b = *(const float4*)(x + grow + 4);
    uint4 v;
    v.x = pack2(a.x, a.y);
    v.y = pack2(a.z, a.w);
    v.z = pack2(b.x, b.y);
    v.w = pack2(b.z, b.w);
    *(uint4*)(bufX + r * XS + c) = v;
  }
  __syncthreads();

  // ---------- stage A: xl = A*W_left^T, xr = A*W_right^T (l=1,2 only) ----------
#pragma unroll
  for (int p = 0; p < 2; ++p) {
    if (p == 1) {
#pragma unroll
      for (int ci = 0; ci < 2; ++ci) {
        int dcol = (wl * 4 + 2 + ci) * 16 + lr;
#pragma unroll
        for (int kk = 0; kk < 4; ++kk) {
          bfa[ci][0][kk] = *(const uint4*)(wsA + 16384     + dcol * CD + kk * 32 + q * 8);
          bfa[ci][1][kk] = *(const uint4*)(wsA + 2 * 16384 + dcol * CD + kk * 32 + q * 8);
        }
      }
    }
#pragma unroll
    for (int rt = 0; rt < 5; ++rt) {
      const int l2f   = (rt >= 2) ? 1 : 0;
      const int rows  = l2f ? 40 : 24;
      const int gbase = l2f ? (rt - 2) * 16 : rt * 16;
      const int boff  = l2f ? 24 : 0;
      int ga = gbase + lr; if (ga > rows - 1) ga = rows - 1;
      const int arow = boff + ga;
      uint4 av[4];
#pragma unroll
      for (int kk = 0; kk < 4; ++kk)
        av[kk] = *(const uint4*)(bufX + arow * XS + kk * 32 + q * 8);
#pragma unroll
      for (int ci = 0; ci < 2; ++ci) {
        int dcol = (wl * 4 + 2 * p + ci) * 16 + lr;
        f32x4 acc = {0.f, 0.f, 0.f, 0.f};
#pragma unroll
        for (int kk = 0; kk < 4; ++kk) {
          acc = __builtin_amdgcn_mfma_f32_16x16x32_bf16(
              __builtin_bit_cast(bf16x8, av[kk]),
              __builtin_bit_cast(bf16x8, bfa[ci][l2f][kk]),
              acc, 0, 0, 0);
        }
#pragma unroll
        for (int reg = 0; reg < 4; ++reg) {
          int gg = gbase + q * 4 + reg;
          if (gg < rows) dstA[(boff + gg) * LS + dcol] = f2b(acc[reg]);
        }
      }
    }
  }
  __syncthreads();

  // ---------- stage B: channel-wise CG tensor product (fp32), 2 ch per b32 ----------
#pragma unroll
  for (int iter = 0; iter < 2; ++iter) {
    int id = iter * 256 + tid;          // 0..511
    int cb = (id & 63) * 2;             // even base channel; wave spans 256B -> 2-way only
    int n  = id >> 6;                   // 0..7
    const u16* pL = sL + n * LS + cb;
    const u16* pR = sR + n * LS + cb;
    float xl1[2][3], xr1[2][3], xl2[2][5], xr2[2][5];
#pragma unroll
    for (int i = 0; i < 3; ++i) {
      u32 vl = *(const u32*)(pL + i * 8 * LS);
      u32 vr = *(const u32*)(pR + i * 8 * LS);
      xl1[0][i] = b2f((u16)vl); xl1[1][i] = b2f((u16)(vl >> 16));
      xr1[0][i] = b2f((u16)vr); xr1[1][i] = b2f((u16)(vr >> 16));
    }
#pragma unroll
    for (int j = 0; j < 5; ++j) {
      u32 vl = *(const u32*)(pL + (24 + j * 8) * LS);
      u32 vr = *(const u32*)(pR + (24 + j * 8) * LS);
      xl2[0][j] = b2f((u16)vl); xl2[1][j] = b2f((u16)(vl >> 16));
      xr2[0][j] = b2f((u16)vr); xr2[1][j] = b2f((u16)(vr >> 16));
    }
    float o0[2], o1[2][3], o2[2][5];
#pragma unroll
    for (int ch = 0; ch < 2; ++ch) {
      float s0 = 0.f;
#pragma unroll
      for (int i = 0; i < 5; ++i)
#pragma unroll
        for (int j = 0; j < 5; ++j)
          s0 += tw.w220[i * 5 + j] * xl2[ch][i] * xr2[ch][j];
      o0[ch] = s0;
      float a1[3] = {0.f, 0.f, 0.f};
#pragma unroll
      for (int i = 0; i < 3; ++i)
#pragma unroll
        for (int j = 0; j < 5; ++j) {
          float pr = xl1[ch][i] * xr2[ch][j];
#pragma unroll
          for (int k = 0; k < 3; ++k) a1[k] += tw.w121[(i * 5 + j) * 3 + k] * pr;
        }
#pragma unroll
      for (int k = 0; k < 3; ++k) o1[ch][k] = a1[k];
      float a2[5] = {0.f, 0.f, 0.f, 0.f, 0.f};
#pragma unroll
      for (int i = 0; i < 3; ++i)
#pragma unroll
        for (int j = 0; j < 3; ++j) {
          float pr = xl1[ch][i] * xr1[ch][j];
#pragma unroll
          for (int k = 0; k < 5; ++k) a2[k] += tw.w112[(i * 3 + j) * 5 + k] * pr;
        }
#pragma unroll
      for (int k = 0; k < 5; ++k) o2[ch][k] = a2[k];
    }
    u16* pT = sTP + n * XS + cb;
    *(u32*)(pT) = pack2(o0[0], o0[1]);
#pragma unroll
    for (int k = 0; k < 3; ++k) *(u32*)(pT + (1 + k) * 8 * XS) = pack2(o1[0][k], o1[1][k]);
#pragma unroll
    for (int k = 0; k < 5; ++k) *(u32*)(pT + (4 + k) * 8 * XS) = pack2(o2[0][k], o2[1][k]);
  }

  // stage-C l=0 B-frags: issue before the barrier so vmcnt overlaps the sync
  const u16* wsf = ws + 6 * 16384;
  uint4 bc0[4], bc1[4];
#pragma unroll
  for (int kk = 0; kk < 4; ++kk) {
    bc0[kk] = *(const uint4*)(wsf + dc0 * CD + kk * 32 + q * 8);
    bc1[kk] = *(const uint4*)(wsf + dc1 * CD + kk * 32 + q * 8);
  }
  __syncthreads();

  // ---------- stage C: out = TP * W_final^T (+ b_final on m=0), store fp32 ----------
#pragma unroll
  for (int l = 0; l < 3; ++l) {
    if (l > 0) {
#pragma unroll
      for (int kk = 0; kk < 4; ++kk) {
        bc0[kk] = *(const uint4*)(wsf + l * 16384 + dc0 * CD + kk * 32 + q * 8);
        bc1[kk] = *(const uint4*)(wsf + l * 16384 + dc1 * CD + kk * 32 + q * 8);
      }
    }
    const int rows   = (l == 0) ? 8 : (l == 1 ? 24 : 40);
    const int soff   = (l == 0) ? 0 : (l == 1 ? 8 : 32);
    const int ntiles = (l == 0) ? 1 : (l == 1 ? 2 : 3);
#pragma unroll
    for (int t = 0; t < 3; ++t) {
      if (t >= ntiles) continue;
      int ga = t * 16 + lr; if (ga > rows - 1) ga = rows - 1;
      const int arow = soff + ga;
      uint4 av[4];
#pragma unroll
      for (int kk = 0; kk < 4; ++kk)
        av[kk] = *(const uint4*)(sTP + arow * XS + kk * 32 + q * 8);
      f32x4 a0 = {0.f, 0.f, 0.f, 0.f};
      f32x4 a1 = {0.f, 0.f, 0.f, 0.f};
#pragma unroll
      for (int kk = 0; kk < 4; ++kk) {
        a0 = __builtin_amdgcn_mfma_f32_16x16x32_bf16(
            __builtin_bit_cast(bf16x8, av[kk]),
            __builtin_bit_cast(bf16x8, bc0[kk]), a0, 0, 0, 0);
        a1 = __builtin_amdgcn_mfma_f32_16x16x32_bf16(
            __builtin_bit_cast(bf16x8, av[kk]),
            __builtin_bit_cast(bf16x8, bc1[kk]), a1, 0, 0, 0);
      }
#pragma unroll
      for (int reg = 0; reg < 4; ++reg) {
        int gg = t * 16 + q * 4 + reg;
        if (gg < rows) {
          int m = l * l + (gg >> 3);
          int n = n0 + (gg & 7);
          if (n < N) {
            float v0 = a0[reg], v1 = a1[reg];
            if (l == 0) { v0 += bias0; v1 += bias1; }
            out[(n * 9 + m) * CD + dc0] = v0;
            out[(n * 9 + m) * CD + dc1] = v1;
          }
        }
      }
    }
  }
}

// =================== host: Wigner-3j (exact port of reference) ===================
typedef std::complex<double> cd;

static double factd(int n) { double r = 1.0; for (int i = 2; i <= n; ++i) r *= i; return r; }

static double su2_cg(int j1, int m1, int j2, int m2, int j3, int m3) {
  if (m3 != m1 + m2) return 0.0;
  int vmin = -j1 + j2 + m3; if (-j1 + m1 > vmin) vmin = -j1 + m1; if (0 > vmin) vmin = 0;
  int vmax = j2 + j3 + m1; if (j3 - j1 + j2 < vmax) vmax = j3 - j1 + j2; if (j3 + m3 < vmax) vmax = j3 + m3;
  double pref = std::sqrt((2.0 * j3 + 1.0) * factd(j3 + j1 - j2) * factd(j3 - j1 + j2)
                          * factd(j1 + j2 - j3) / factd(j1 + j2 + j3 + 1)
                          * factd(j3 + m3) * factd(j3 - m3)
                          / (factd(j1 - m1) * factd(j1 + m1) * factd(j2 - m2) * factd(j2 + m2)));
  double s = 0.0;
  for (int v = vmin; v <= vmax; ++v) {
    double sgn = ((v + j2 + m2) & 1) ? -1.0 : 1.0;
    s += sgn / factd(v) * factd(j2 + j3 + m1 - v) * factd(j1 - m1 + v)
         / (factd(j3 - j1 + j2 - v) * factd(j3 + m3 - v) * factd(v + j1 - j2 - m3));
  }
  return pref * s;
}

static void qmat(int l, cd q[5][5]) {
  for (int a = 0; a < 5; ++a) for (int b = 0; b < 5; ++b) q[a][b] = 0.0;
  const double is2 = 1.0 / std::sqrt(2.0);
  for (int m = -l; m < 0; ++m) {
    q[l + m][l - m] = is2;            // q[l+m, l+|m|]
    q[l + m][l + m] = cd(0.0, -is2);  // q[l+m, l-|m|]
  }
  q[l][l] = 1.0;
  for (int m = 1; m <= l; ++m) {
    double s = (m & 1) ? -1.0 : 1.0;
    q[l + m][l + m] = s * is2;
    q[l + m][l - m] = cd(0.0, s * is2);
  }
  cd f(1.0, 0.0);
  for (int i = 0; i < l; ++i) f *= cd(0.0, -1.0);  // (-1j)^l
  for (int a = 0; a < 5; ++a) for (int b = 0; b < 5; ++b) q[a][b] *= f;
}

static void wigner3j(int l1, int l2, int l3, double* C) {  // flat [d1][d2][d3]
  int d1 = 2 * l1 + 1, d2 = 2 * l2 + 1, d3 = 2 * l3 + 1;
  cd Q1[5][5], Q2[5][5], Q3[5][5];
  qmat(l1, Q1); qmat(l2, Q2); qmat(l3, Q3);
  cd Csu2[5][5][5];
  for (int i = 0; i < d1; ++i)
    for (int k = 0; k < d2; ++k)
      for (int n = 0; n < d3; ++n)
        Csu2[i][k][n] = su2_cg(l1, i - l1, l2, k - l2, l3, n - l3);
  double norm = 0.0;
  for (int j = 0; j < d1; ++j)
    for (int lx = 0; lx < d2; ++lx)
      for (int m = 0; m < d3; ++m) {
        cd acc(0.0, 0.0);
        for (int i = 0; i < d1; ++i)
          for (int k = 0; k < d2; ++k)
            for (int n = 0; n < d3; ++n)
              acc += Q1[i][j] * Q2[k][lx] * std::conj(Q3[n][m]) * Csu2[i][k][n];
        C[(j * d2 + lx) * d3 + m] = acc.real();
        norm += acc.real() * acc.real();
      }
  norm = std::sqrt(norm);
  for (int t = 0; t < d1 * d2 * d3; ++t) C[t] /= norm;
}

extern "C" void kernel_launch(void* const* d_in, const int* in_sizes, int n_in,
                              void* d_out, int out_size, void* d_ws, size_t ws_size,
                              hipStream_t stream) {
  const float* x    = (const float*)d_in[0];
  const float* Wl   = (const float*)d_in[1];
  const float* Wr   = (const float*)d_in[3];
  const float* Wf   = (const float*)d_in[5];
  const float* bfin = (const float*)d_in[6];
  float* out = (float*)d_out;
  const int N = in_sizes[0] / (9 * CD);

  TPW tw;
  double c220[25], c121[45], c112[45];
  wigner3j(2, 2, 0, c220);
  wigner3j(1, 2, 1, c121);
  wigner3j(1, 1, 2, c112);
  const double a1 = std::sqrt(3.0), a2 = std::sqrt(5.0);
  for (int i = 0; i < 25; ++i) tw.w220[i] = (float)c220[i];          // alpha = 1
  for (int i = 0; i < 45; ++i) tw.w121[i] = (float)(a1 * c121[i]);
  for (int i = 0; i < 45; ++i) tw.w112[i] = (float)(a2 * c112[i]);

  u16* ws = (u16*)d_ws;  // 147456 bf16 = 294912 B
  cvt_weights_kernel<<<72, 256, 0, stream>>>(Wl, Wr, Wf, ws);
  int grid = (N + TILE_N - 1) / TILE_N;
  fused_kernel<<<grid, 256, 0, stream>>>(x, ws, bfin, out, N, tw);
}